// Round 5
// baseline (341.927 us; speedup 1.0000x reference)
//
#include <hip/hip_runtime.h>

// HashRoutedSSMLayer: B=8,S=2048,D=1024,N=256,H=512,E=8 — fp32 in/out.
// Round 5: double-buffered async K-loop (prefetch tile k+1 during compute of
// tile k, ONE barrier/iter), unrolled scan fast path. BK=32, LDS 32KB.

#define TOKS 16384
#define RPAD 16512      // TOKS + 128 pad rows for tile overread
#define DD   1024
#define NN   256
#define HH   512
#define MAXTILES  136   // sum ceil(ce/128) <= 128+8
#define MAXCHUNKS 1088  // sum ceil(n_g/16) <= 1024+64
#define CHUNK 16

typedef short short8 __attribute__((ext_vector_type(8)));
typedef float floatx4 __attribute__((ext_vector_type(4)));
typedef _Float16 half_t;

#define AS_GLOBAL __attribute__((address_space(1)))
#define AS_LDS    __attribute__((address_space(3)))

__device__ __forceinline__ void gl_lds16(const void* g, void* l) {
    __builtin_amdgcn_global_load_lds((const AS_GLOBAL void*)g, (AS_LDS void*)l, 16, 0, 0);
}

__device__ __forceinline__ unsigned short f2bf(float f) {
    union { float f; unsigned u; } c; c.f = f;
    unsigned r = c.u + 0x7FFF + ((c.u >> 16) & 1);
    return (unsigned short)(r >> 16);
}
__device__ __forceinline__ int route_of(int token) {
    unsigned x = (unsigned)token;
    x ^= x >> 16; x *= 2246822507u; x ^= x >> 13; x *= 3266489909u; x ^= x >> 16;
    return (int)(x & 7u);
}
__device__ __forceinline__ float sigm(float v) { return 1.0f / (1.0f + __expf(-v)); }
__device__ __forceinline__ float ftanh(float v) {
    float e = __expf(2.0f * v);          // inf-safe: v>>0 -> 1, v<<0 -> -1
    return 1.0f - 2.0f / (e + 1.0f);
}

// ---------------- K1: per-row route histogram ----------------
__global__ void k_route(const int* __restrict__ tok, int* __restrict__ cnt) {
    int b = blockIdx.x, tid = threadIdx.x;
    __shared__ int lc[256 * 8];
    #pragma unroll
    for (int e = 0; e < 8; e++) lc[tid * 8 + e] = 0;
    #pragma unroll
    for (int i = 0; i < 8; i++) {
        int e = route_of(tok[b * 2048 + tid * 8 + i]);
        lc[tid * 8 + e]++;
    }
    __syncthreads();
    if (tid < 8) {
        int s = 0;
        for (int t = 0; t < 256; t++) s += lc[t * 8 + tid];
        cnt[b * 8 + tid] = s;
    }
}

// ---------------- K2: offsets + tile table + chunk table ----------------
__global__ void k_offsets(const int* __restrict__ cnt, int* __restrict__ grpoff,
                          int* __restrict__ tileE, int* __restrict__ tileS,
                          int* __restrict__ tileR,
                          int* __restrict__ cGrp, int* __restrict__ cStart,
                          int* __restrict__ cLen, int* __restrict__ gBase,
                          int* __restrict__ meta) {
    __shared__ int sc[64], ce[8], eoff[9], etile[9], gb[65], go[64];
    int tid = threadIdx.x;
    if (tid < 64) sc[tid] = cnt[tid];
    __syncthreads();
    if (tid < 8) { int s = 0; for (int b = 0; b < 8; b++) s += sc[b * 8 + tid]; ce[tid] = s; }
    __syncthreads();
    if (tid == 0) {
        eoff[0] = 0; etile[0] = 0;
        for (int e = 0; e < 8; e++) {
            eoff[e + 1] = eoff[e] + ce[e];
            etile[e + 1] = etile[e] + (ce[e] + 127) / 128;
        }
        meta[0] = etile[8];
        gb[0] = 0;
        for (int g = 0; g < 64; g++) gb[g + 1] = gb[g] + (sc[g] + CHUNK - 1) / CHUNK;
        meta[1] = gb[64];
    }
    __syncthreads();
    if (tid < 64) {
        int b = tid >> 3, e = tid & 7;
        int run = eoff[e];
        for (int b2 = 0; b2 < b; b2++) run += sc[b2 * 8 + e];
        go[tid] = run;
        grpoff[tid] = run;
    }
    __syncthreads();
    if (tid < 8) {   // tiles for expert tid
        int e = tid, st = eoff[e], c = ce[e], t0 = etile[e];
        for (int i = 0, k = 0; i < c; i += 128, k++) {
            tileE[t0 + k] = e; tileS[t0 + k] = st + i;
            tileR[t0 + k] = (c - i < 128) ? (c - i) : 128;
        }
    }
    if (tid < 64) {  // chunks for group tid
        int g = tid, n = sc[g], base = gb[g], s0 = go[g];
        gBase[g] = base;
        for (int i = 0, c = 0; i < n; i += CHUNK, c++) {
            cGrp[base + c] = g;
            cStart[base + c] = s0 + i;
            cLen[base + c] = (n - i < CHUNK) ? (n - i) : CHUNK;
        }
    }
}

// ---------------- K3: stable counting-sort scatter ----------------
__global__ void k_scatter(const int* __restrict__ tok, const int* __restrict__ grpoff,
                          int* __restrict__ perm) {
    int b = blockIdx.x, tid = threadIdx.x;
    __shared__ int lh[8 * 256];
    int r[8];
    int myc[8] = {0,0,0,0,0,0,0,0};
    #pragma unroll
    for (int i = 0; i < 8; i++) {
        int e = route_of(tok[b * 2048 + tid * 8 + i]);
        r[i] = e; myc[e]++;
    }
    #pragma unroll
    for (int e = 0; e < 8; e++) lh[e * 256 + tid] = myc[e];
    __syncthreads();
    for (int e = 0; e < 8; e++) {
        for (int off = 1; off < 256; off <<= 1) {
            int add = (tid >= off) ? lh[e * 256 + tid - off] : 0;
            __syncthreads();
            lh[e * 256 + tid] += add;
            __syncthreads();
        }
    }
    int basep[8];
    #pragma unroll
    for (int e = 0; e < 8; e++) basep[e] = grpoff[b * 8 + e] + lh[e * 256 + tid] - myc[e];
    #pragma unroll
    for (int i = 0; i < 8; i++) {
        int e = r[i];
        perm[basep[e]++] = b * 2048 + tid * 8 + i;
    }
}

// ---------------- K4: weights fp32 -> bf16 (W12 = [Win|Wsin] concat) ----------------
__global__ void k_cvtw(const float* __restrict__ Win, const float* __restrict__ Wsin,
                       const float* __restrict__ Wsout, const float* __restrict__ Wout,
                       unsigned short* __restrict__ W12, unsigned short* __restrict__ Wso,
                       unsigned short* __restrict__ Wo) {
    const int C12 = 8 * 768 * 1024 / 4, CSO = 8 * 1024 * 512 / 4, CWO = 8 * 1024 * 256 / 4;
    int c = blockIdx.x * 256 + threadIdx.x;
    float4 v; unsigned short* dst;
    if (c < C12) {
        int d = c * 4;
        int e = d / (768 * 1024);
        int rem = d - e * (768 * 1024);
        int r = rem >> 10, k = rem & 1023;
        const float* src = (r < 256) ? (Win + (((size_t)e * 256 + r) << 10) + k)
                                     : (Wsin + (((size_t)e * 512 + (r - 256)) << 10) + k);
        v = *(const float4*)src;
        dst = W12 + d;
    } else if (c < C12 + CSO) {
        int d = (c - C12) * 4;
        v = *(const float4*)(Wsout + d);
        dst = Wso + d;
    } else if (c < C12 + CSO + CWO) {
        int d = (c - C12 - CSO) * 4;
        v = *(const float4*)(Wout + d);
        dst = Wo + d;
    } else return;
    ushort4 o;
    o.x = f2bf(v.x); o.y = f2bf(v.y); o.z = f2bf(v.z); o.w = f2bf(v.w);
    *(ushort4*)dst = o;
}

// ---------------- K5: gather x into sorted bf16 rows + zero pads ----------------
__global__ void k_gather(const float* __restrict__ x, const int* __restrict__ perm,
                         unsigned short* __restrict__ Xs, unsigned short* __restrict__ SHb,
                         unsigned short* __restrict__ Yb) {
    int r = blockIdx.x, t = threadIdx.x;
    if (r < TOKS) {
        int tok = perm[r];
        float4 v = *(const float4*)(x + (size_t)tok * 1024 + t * 4);
        ushort4 o;
        o.x = f2bf(v.x); o.y = f2bf(v.y); o.z = f2bf(v.z); o.w = f2bf(v.w);
        *(ushort4*)(Xs + (size_t)r * 1024 + t * 4) = o;
    } else {
        ushort4 z = {0, 0, 0, 0};
        *(ushort4*)(Xs + (size_t)r * 1024 + t * 4) = z;
        if (t < 128) *(ushort4*)(SHb + (size_t)r * 512 + t * 4) = z;
        if (t < 64)  *(ushort4*)(Yb + (size_t)r * 256 + t * 4) = z;
    }
}

// ---------------- MFMA grouped GEMM, BM=128 BN=128 BK=32, double-buffered ----------------
// MODE 0: A=Xs (K=1024), B=W12 [e][768][1024]: n<256 -> Ub fp16; else silu -> SHb bf16
// MODE 1: A=SHb (K=512), B=Wso [e][1024][512]: regions a,b,c,d -> fp16 gates
// MODE 2: A=Yb (K=256),  B=Wo  [e][1024][256]: scatter fp32 out via perm
template<int MODE, int KD>
__global__ __launch_bounds__(256, 4)
void k_mfma(const unsigned short* __restrict__ A, const unsigned short* __restrict__ Bw,
            const int* __restrict__ perm, const float* __restrict__ dparam,
            half_t* __restrict__ Ub, unsigned short* __restrict__ SHb,
            half_t* __restrict__ Aa, half_t* __restrict__ Wg,
            half_t* __restrict__ Cc, half_t* __restrict__ Sk,
            float* __restrict__ out,
            const int* __restrict__ tileE, const int* __restrict__ tileS,
            const int* __restrict__ tileR, const int* __restrict__ meta) {
    int mt = blockIdx.x;
    if (mt >= meta[0]) return;
    const int e = tileE[mt], pos0 = tileS[mt], rows = tileR[mt];
    const int col0 = blockIdx.y * 128;
    const int tid = threadIdx.x;
    const int w = tid >> 6, lane = tid & 63, quad = lane >> 4, l15 = lane & 15;
    const int wm = w & 1, wn = w >> 1;
    constexpr int NOUT = (MODE == 0) ? 768 : 1024;

    // [buf=2][row=128][32 elems] per operand; 32 KB total
    __shared__ unsigned short As[2 * 128 * 32];
    __shared__ unsigned short Bs[2 * 128 * 32];

    const int r0 = tid >> 2, c8 = (tid & 3) * 8;
    const unsigned short* ga = A + (size_t)(pos0 + r0) * KD + c8;
    const unsigned short* gb = Bw + ((size_t)e * NOUT + col0 + r0) * KD + c8;

    floatx4 acc[4][4] = {};

    int aoff[4], boff[4];
    #pragma unroll
    for (int i = 0; i < 4; i++) aoff[i] = (wm * 64 + i * 16 + l15) * 32 + quad * 8;
    #pragma unroll
    for (int j = 0; j < 4; j++) boff[j] = (wn * 64 + j * 16 + l15) * 32 + quad * 8;

    // stage 32-K slab k0 into buffer `buf` (4 async 16B issues per thread)
    auto stage = [&](int buf, int k0) {
        gl_lds16(ga + k0,                   As + buf * 4096 + w * 512);
        gl_lds16(ga + (size_t)64 * KD + k0, As + buf * 4096 + 2048 + w * 512);
        gl_lds16(gb + k0,                   Bs + buf * 4096 + w * 512);
        gl_lds16(gb + (size_t)64 * KD + k0, Bs + buf * 4096 + 2048 + w * 512);
    };

    stage(0, 0);  // prologue prefetch
    #pragma unroll
    for (int k0 = 0; k0 < KD; k0 += 32) {
        const int cur = (k0 >> 5) & 1;
        __syncthreads();                 // drains vmcnt: cur tile landed; prev reads done
        if (k0 + 32 < KD) stage(1 - cur, k0 + 32);  // prefetch next while computing cur
        short8 af[4], bf[4];
        #pragma unroll
        for (int i = 0; i < 4; i++) af[i] = *(const short8*)(As + cur * 4096 + aoff[i]);
        #pragma unroll
        for (int j = 0; j < 4; j++) bf[j] = *(const short8*)(Bs + cur * 4096 + boff[j]);
        #pragma unroll
        for (int i = 0; i < 4; i++)
            #pragma unroll
            for (int j = 0; j < 4; j++)
                acc[i][j] = __builtin_amdgcn_mfma_f32_16x16x32_bf16(af[i], bf[j], acc[i][j], 0, 0, 0);
    }

    // epilogue: C/D layout: col = l15 (n), row = quad*4 + reg (m), per 16x16 tile
    #pragma unroll
    for (int i = 0; i < 4; i++) {
        #pragma unroll
        for (int r = 0; r < 4; r++) {
            int m = wm * 64 + i * 16 + quad * 4 + r;
            if (m >= rows) continue;
            size_t row = (size_t)(pos0 + m);
            if (MODE == 0) {
                if (col0 < 256) {
                    #pragma unroll
                    for (int j = 0; j < 4; j++) {
                        int n = col0 + wn * 64 + j * 16 + l15;
                        Ub[row * 256 + n] = (half_t)acc[i][j][r];
                    }
                } else {
                    #pragma unroll
                    for (int j = 0; j < 4; j++) {
                        int n = col0 - 256 + wn * 64 + j * 16 + l15;
                        float v = acc[i][j][r];
                        SHb[row * 512 + n] = f2bf(v * sigm(v));
                    }
                }
            } else if (MODE == 1) {
                int region = col0 >> 8;  // block-uniform
                #pragma unroll
                for (int j = 0; j < 4; j++) {
                    int n0 = (col0 & 255) + wn * 64 + j * 16 + l15;
                    size_t idx = row * 256 + (size_t)n0;
                    float v = acc[i][j][r];
                    if (region == 0) {
                        Aa[idx] = (half_t)sigm(v);
                    } else if (region == 1) {
                        Wg[idx] = (half_t)(ftanh(v) * (float)Ub[idx]);
                    } else if (region == 2) {
                        Cc[idx] = (half_t)ftanh(v);
                    } else {
                        Sk[idx] = (half_t)(dparam[e * 256 + n0] * sigm(v) * (float)Ub[idx]);
                    }
                }
            } else {
                int tok = perm[row];
                #pragma unroll
                for (int j = 0; j < 4; j++) {
                    int n = col0 + wn * 64 + j * 16 + l15;
                    out[(size_t)tok * 1024 + n] = acc[i][j][r];
                }
            }
        }
    }
}

// ---------------- K8a: chunk-local affine composition ----------------
__global__ void k_scanA(const half_t* __restrict__ Aa, const half_t* __restrict__ Wg,
                        const int* __restrict__ cStart, const int* __restrict__ cLen,
                        const int* __restrict__ meta,
                        float* __restrict__ SA, float* __restrict__ SQ) {
    int id = blockIdx.x;
    if (id >= meta[1]) return;
    int t = threadIdx.x;
    int s0 = cStart[id], L = cLen[id];
    size_t idx = (size_t)s0 * 256 + t;
    float p = 1.0f, q = 0.0f;
    if (L == CHUNK) {  // fast path: all loads issued up-front
        float av[CHUNK], wv[CHUNK];
        #pragma unroll
        for (int i = 0; i < CHUNK; i++) {
            av[i] = (float)Aa[idx + (size_t)i * 256];
            wv[i] = (float)Wg[idx + (size_t)i * 256];
        }
        #pragma unroll
        for (int i = 0; i < CHUNK; i++) { q = av[i] * q + wv[i]; p *= av[i]; }
    } else {
        for (int i = 0; i < L; i++) {
            float a = (float)Aa[idx], ww = (float)Wg[idx];
            q = a * q + ww;
            p *= a;
            idx += 256;
        }
    }
    SA[(size_t)id * 256 + t] = p;
    SQ[(size_t)id * 256 + t] = q;
}

// ---------------- K8b: per-group serial combine -> chunk h_in ----------------
__global__ void k_scanB(const float* __restrict__ SA, const float* __restrict__ SQ,
                        const int* __restrict__ gBase, const int* __restrict__ cnt,
                        float* __restrict__ Hin) {
    int g = blockIdx.x, t = threadIdx.x;
    int base = gBase[g], nch = (cnt[g] + CHUNK - 1) / CHUNK;
    float h = 0.0f;
    for (int c = 0; c < nch; c++) {
        size_t k = (size_t)(base + c) * 256 + t;
        Hin[k] = h;
        h = SA[k] * h + SQ[k];
    }
}

// ---------------- K8c: re-scan with h_in, emit y (bf16) ----------------
__global__ void k_scanC(const half_t* __restrict__ Aa, const half_t* __restrict__ Wg,
                        const half_t* __restrict__ Cc, const half_t* __restrict__ Sk,
                        const int* __restrict__ cStart, const int* __restrict__ cLen,
                        const int* __restrict__ meta, const float* __restrict__ Hin,
                        unsigned short* __restrict__ Yb) {
    int id = blockIdx.x;
    if (id >= meta[1]) return;
    int t = threadIdx.x;
    int s0 = cStart[id], L = cLen[id];
    float h = Hin[(size_t)id * 256 + t];
    size_t idx = (size_t)s0 * 256 + t;
    if (L == CHUNK) {  // fast path
        float av[CHUNK], wv[CHUNK], cv[CHUNK], sv[CHUNK];
        #pragma unroll
        for (int i = 0; i < CHUNK; i++) {
            size_t k = idx + (size_t)i * 256;
            av[i] = (float)Aa[k]; wv[i] = (float)Wg[k];
            cv[i] = (float)Cc[k]; sv[i] = (float)Sk[k];
        }
        #pragma unroll
        for (int i = 0; i < CHUNK; i++) {
            h = av[i] * h + wv[i];
            Yb[idx + (size_t)i * 256] = f2bf(cv[i] * h + sv[i]);
        }
    } else {
        for (int i = 0; i < L; i++) {
            float a = (float)Aa[idx], ww = (float)Wg[idx];
            float c = (float)Cc[idx], sk = (float)Sk[idx];
            h = a * h + ww;
            Yb[idx] = f2bf(c * h + sk);
            idx += 256;
        }
    }
}

extern "C" void kernel_launch(void* const* d_in, const int* in_sizes, int n_in,
                              void* d_out, int out_size, void* d_ws, size_t ws_size,
                              hipStream_t stream) {
    const float* xin   = (const float*)d_in[0];
    const int*   tok   = (const int*)d_in[1];
    const float* Win   = (const float*)d_in[2];
    const float* Wsin  = (const float*)d_in[3];
    const float* Wsout = (const float*)d_in[4];
    const float* Wout  = (const float*)d_in[5];
    const float* dpar  = (const float*)d_in[6];
    float* out = (float*)d_out;

    size_t off = 0;
    char* base = (char*)d_ws;
    auto alloc = [&](size_t bytes) -> void* {
        void* p = base + off;
        off += (bytes + 255) & ~(size_t)255;
        return p;
    };
    half_t*         Ub  = (half_t*)alloc((size_t)RPAD * NN * 2);
    unsigned short* SHb = (unsigned short*)alloc((size_t)RPAD * HH * 2);
    unsigned short* Xs  = (unsigned short*)alloc((size_t)RPAD * DD * 2);
    unsigned short* Yb  = (unsigned short*)alloc((size_t)RPAD * NN * 2);
    half_t* Aa = (half_t*)alloc((size_t)TOKS * NN * 2);
    half_t* Wg = (half_t*)alloc((size_t)TOKS * NN * 2);
    half_t* Cc = (half_t*)alloc((size_t)TOKS * NN * 2);
    half_t* Sk = (half_t*)alloc((size_t)TOKS * NN * 2);
    unsigned short* W12 = (unsigned short*)alloc((size_t)8 * 768 * 1024 * 2);
    unsigned short* Wso = (unsigned short*)alloc((size_t)8 * 1024 * 512 * 2);
    unsigned short* Wo  = (unsigned short*)alloc((size_t)8 * 1024 * 256 * 2);
    float* SA  = (float*)alloc((size_t)MAXCHUNKS * 256 * 4);
    float* SQ  = (float*)alloc((size_t)MAXCHUNKS * 256 * 4);
    float* Hin = (float*)alloc((size_t)MAXCHUNKS * 256 * 4);
    int* perm   = (int*)alloc(TOKS * 4);
    int* cnt    = (int*)alloc(64 * 4);
    int* grpoff = (int*)alloc(64 * 4);
    int* tileE  = (int*)alloc(MAXTILES * 4);
    int* tileS  = (int*)alloc(MAXTILES * 4);
    int* tileR  = (int*)alloc(MAXTILES * 4);
    int* cGrp   = (int*)alloc(MAXCHUNKS * 4);
    int* cStart = (int*)alloc(MAXCHUNKS * 4);
    int* cLen   = (int*)alloc(MAXCHUNKS * 4);
    int* gBase  = (int*)alloc(64 * 4);
    int* meta   = (int*)alloc(16 * 4);

    k_route<<<8, 256, 0, stream>>>(tok, cnt);
    k_offsets<<<1, 256, 0, stream>>>(cnt, grpoff, tileE, tileS, tileR,
                                     cGrp, cStart, cLen, gBase, meta);
    k_scatter<<<8, 256, 0, stream>>>(tok, grpoff, perm);
    k_cvtw<<<12288, 256, 0, stream>>>(Win, Wsin, Wsout, Wout, W12, Wso, Wo);
    k_gather<<<RPAD, 256, 0, stream>>>(xin, perm, Xs, SHb, Yb);

    k_mfma<0, 1024><<<dim3(MAXTILES, 6), 256, 0, stream>>>(Xs, W12, perm, dpar,
        Ub, SHb, Aa, Wg, Cc, Sk, out, tileE, tileS, tileR, meta);
    k_mfma<1, 512><<<dim3(MAXTILES, 8), 256, 0, stream>>>(SHb, Wso, perm, dpar,
        Ub, SHb, Aa, Wg, Cc, Sk, out, tileE, tileS, tileR, meta);

    k_scanA<<<MAXCHUNKS, 256, 0, stream>>>(Aa, Wg, cStart, cLen, meta, SA, SQ);
    k_scanB<<<64, 256, 0, stream>>>(SA, SQ, gBase, cnt, Hin);
    k_scanC<<<MAXCHUNKS, 256, 0, stream>>>(Aa, Wg, Cc, Sk, cStart, cLen, meta, Hin, Yb);

    k_mfma<2, 256><<<dim3(MAXTILES, 8), 256, 0, stream>>>(Yb, Wo, perm, dpar,
        Ub, SHb, Aa, Wg, Cc, Sk, out, tileE, tileS, tileR, meta);
}